// Round 6
// baseline (710.610 us; speedup 1.0000x reference)
//
#include <hip/hip_runtime.h>
#include <hip/hip_bf16.h>
#include <math.h>

typedef __hip_bfloat16 bf16;
typedef unsigned short u16;
#define DEV __device__ __forceinline__

DEV float tofl(float v){ return v; }
DEV bf16  f2b(float v){ return __float2bfloat16(v); }
DEV u16   f2bu(float v){ bf16 h = f2b(v); u16 u; __builtin_memcpy(&u,&h,2); return u; }
DEV float u2f(u16 u){ bf16 h; __builtin_memcpy(&h,&u,2); return __bfloat162float(h); }

static constexpr int Cc=256, Nn=4096, Mm=32;
static constexpr size_t ACT = (size_t)8*Cc*Nn;
static constexpr float EPSc = 1e-6f;

typedef __attribute__((ext_vector_type(8))) __bf16 bf16x8;
typedef __attribute__((ext_vector_type(4))) float  f32x4;

// ============================================================================
// MFMA GEMM building blocks (128x128 tile, BK=64, 4 waves, 16x16x32 bf16,
// XOR-swizzled LDS, double-buffered, load-early/write-late). Proven round 2/3.
// ============================================================================
struct StageRegs { int4 a[4], b[4]; };

DEV void stage_load(const u16* __restrict__ gA, int ldA,
                    const u16* __restrict__ gB, int ldB, int tid, StageRegs& r)
{
  int row = tid>>3, g = tid&7;
#pragma unroll
  for(int i=0;i<4;i++){
    r.a[i] = *(const int4*)(gA + (size_t)(row+32*i)*ldA + g*8);
    r.b[i] = *(const int4*)(gB + (size_t)(row+32*i)*ldB + g*8);
  }
}
DEV void stage_write(u16* __restrict__ sA, u16* __restrict__ sB,
                     int tid, const StageRegs& r)
{
  int row = tid>>3, g = tid&7;
#pragma unroll
  for(int i=0;i<4;i++){
    int rr = row+32*i;
    int gg = ((g ^ (rr&7))<<3);
    *(int4*)(sA + rr*64 + gg) = r.a[i];
    *(int4*)(sB + rr*64 + gg) = r.b[i];
  }
}

// ---- plain bf16 GEMM.  OMODE 3: bf16 c-major out (V, s1).
template<int KDIM, int OMODE>
__global__ __launch_bounds__(256,2) void gemm_bf16(
    const u16* __restrict__ A, long sAb,
    const u16* __restrict__ B,
    float* __restrict__ Cf, u16* __restrict__ Cb,
    const float* __restrict__ bia, const float* __restrict__ scl,
    const float* __restrict__ sht)
{
  __shared__ __align__(16) u16 sA[2][8192];
  __shared__ __align__(16) u16 sB[2][8192];
  int tid = threadIdx.x;
  int nt = blockIdx.x, mt = blockIdx.y, b = blockIdx.z;
  const u16* gA = A + (size_t)b*sAb + (size_t)mt*128*KDIM;
  const u16* gB = B + ((size_t)b*4096 + (size_t)nt*128)*KDIM;
  int w = tid>>6, l = tid&63;
  int wr = w>>1, wc = w&1;
  int l15 = l&15, lg = l>>4;
  f32x4 acc[4][4] = {};
  StageRegs r;
  stage_load(gA, KDIM, gB, KDIM, tid, r);
  stage_write(sA[0], sB[0], tid, r);
  __syncthreads();
  constexpr int NT = KDIM/64;
  for(int t=0;t<NT;t++){
    int cur = t&1;
    if(t+1<NT) stage_load(gA + (t+1)*64, KDIM, gB + (t+1)*64, KDIM, tid, r);
#pragma unroll
    for(int ks=0;ks<2;ks++){
      bf16x8 af[4], bfr[4];
#pragma unroll
      for(int m=0;m<4;m++){
        int row = wr*64 + m*16 + l15;
        int g = ks*4 + lg;
        af[m] = *(const bf16x8*)(&sA[cur][row*64 + ((g^(row&7))<<3)]);
      }
#pragma unroll
      for(int nn=0;nn<4;nn++){
        int row = wc*64 + nn*16 + l15;
        int g = ks*4 + lg;
        bfr[nn] = *(const bf16x8*)(&sB[cur][row*64 + ((g^(row&7))<<3)]);
      }
#pragma unroll
      for(int m=0;m<4;m++)
#pragma unroll
        for(int nn=0;nn<4;nn++)
          acc[m][nn] = __builtin_amdgcn_mfma_f32_16x16x32_bf16(af[m], bfr[nn], acc[m][nn], 0,0,0);
    }
    if(t+1<NT) stage_write(sA[cur^1], sB[cur^1], tid, r);
    __syncthreads();
  }
  int obase = mt*128 + wr*64;
  int nbase = nt*128 + wc*64;
  if (OMODE==0){
    size_t Mrows = (size_t)gridDim.y*128;
#pragma unroll
    for(int m=0;m<4;m++)
#pragma unroll
      for(int nn=0;nn<4;nn++){
        int o_ = obase + m*16 + (lg<<2);
        int n_ = nbase + nn*16 + l15;
        float* dst = Cf + (((size_t)b*Mrows + o_)<<12) + n_;
#pragma unroll
        for(int i=0;i<4;i++) dst[(size_t)i<<12] = acc[m][nn][i];
      }
  } else {   // OMODE 3: bf16 c-major
    size_t Mrows = (size_t)gridDim.y*128;
#pragma unroll
    for(int m=0;m<4;m++)
#pragma unroll
      for(int nn=0;nn<4;nn++){
        int o_ = obase + m*16 + (lg<<2);
        int n_ = nbase + nn*16 + l15;
        u16* dst = Cb + (((size_t)b*Mrows + o_)<<12) + n_;
#pragma unroll
        for(int i=0;i<4;i++) dst[(size_t)i<<12] = f2bu(acc[m][nn][i]);
      }
  }
}

// ---- Q/K fused MFMA conv + softplus. A = [qw(32); kw(32); pad(64)] bf16.
__global__ __launch_bounds__(256,2) void qk_gemm(
    const u16* __restrict__ Aqk, const u16* __restrict__ B,
    float* __restrict__ Qf, float* __restrict__ Kf, u16* __restrict__ Kb)
{
  __shared__ __align__(16) u16 sA[2][8192];
  __shared__ __align__(16) u16 sB[2][8192];
  int tid = threadIdx.x;
  int nt = blockIdx.x, b = blockIdx.z;
  const u16* gA = Aqk;
  const u16* gB = B + ((size_t)b*4096 + (size_t)nt*128)*256;
  int w = tid>>6, l = tid&63;
  int wr = w>>1, wc = w&1;
  int l15 = l&15, lg = l>>4;
  f32x4 acc[4][4] = {};
  StageRegs r;
  stage_load(gA, 256, gB, 256, tid, r);
  stage_write(sA[0], sB[0], tid, r);
  __syncthreads();
  for(int t=0;t<4;t++){
    int cur = t&1;
    if(t+1<4) stage_load(gA + (t+1)*64, 256, gB + (t+1)*64, 256, tid, r);
#pragma unroll
    for(int ks=0;ks<2;ks++){
      bf16x8 af[4], bfr[4];
#pragma unroll
      for(int m=0;m<4;m++){
        int row = wr*64 + m*16 + l15;
        int g = ks*4 + lg;
        af[m] = *(const bf16x8*)(&sA[cur][row*64 + ((g^(row&7))<<3)]);
      }
#pragma unroll
      for(int nn=0;nn<4;nn++){
        int row = wc*64 + nn*16 + l15;
        int g = ks*4 + lg;
        bfr[nn] = *(const bf16x8*)(&sB[cur][row*64 + ((g^(row&7))<<3)]);
      }
#pragma unroll
      for(int m=0;m<4;m++)
#pragma unroll
        for(int nn=0;nn<4;nn++)
          acc[m][nn] = __builtin_amdgcn_mfma_f32_16x16x32_bf16(af[m], bfr[nn], acc[m][nn], 0,0,0);
    }
    if(t+1<4) stage_write(sA[cur^1], sB[cur^1], tid, r);
    __syncthreads();
  }
  if (wr!=0) return;                       // rows 64-127 are padding
  int nbase = nt*128 + wc*64;
#pragma unroll
  for(int m=0;m<4;m++)
#pragma unroll
    for(int nn=0;nn<4;nn++){
      int o_ = m*16 + (lg<<2);             // 0..63
      int n_ = nbase + nn*16 + l15;
#pragma unroll
      for(int i=0;i<4;i++){
        float a = acc[m][nn][i];
        a = fmaxf(a,0.f) + log1pf(expf(-fabsf(a)));     // softplus
        if (m<2){                                        // Q rows 0..31
          Qf[(((size_t)b*32 + o_+i)<<12) + n_] = a;
        } else {                                         // K rows 32..63
          int kr = o_+i-32;
          Kf[(((size_t)b*32 + kr)<<12) + n_] = a;
          Kb[(((size_t)b*32 + kr)<<12) + n_] = f2bu(a);
        }
      }
    }
}

// ---- KV = K·V^T via MFMA, reduction over contiguous n (c-major operands).
__global__ __launch_bounds__(256,2) void kv_gemm(const u16* __restrict__ Kb,
    const u16* __restrict__ Vb, float* __restrict__ Cp)
{
  __shared__ __align__(16) u16 sA[2][8192];
  __shared__ __align__(16) u16 sB[2][8192];
  int tid = threadIdx.x;
  int nt = blockIdx.x;
  int b  = blockIdx.z >> 4, ks = blockIdx.z & 15;
  const u16* gA = Kb + ((size_t)b*32)*4096 + ks*256;
  const u16* gB = Vb + ((size_t)b*256 + (size_t)nt*128)*4096 + ks*256;
  int row = tid>>3, g = tid&7;
  int w = tid>>6, l = tid&63;
  int wr = w>>1, wc = w&1;
  int l15 = l&15, lg = l>>4;
  f32x4 acc[4][4] = {};
  StageRegs r;
#define KV_LOAD(koff) do { \
    _Pragma("unroll") \
    for(int i=0;i<4;i++){ \
      r.a[i] = *(const int4*)(gA + (size_t)row*4096 + (koff) + g*8); \
      r.b[i] = *(const int4*)(gB + (size_t)(row+32*i)*4096 + (koff) + g*8); \
    } } while(0)
  KV_LOAD(0);
  stage_write(sA[0], sB[0], tid, r);
  __syncthreads();
  for(int t=0;t<4;t++){
    int cur = t&1;
    if(t+1<4) KV_LOAD((t+1)*64);
#pragma unroll
    for(int kss=0;kss<2;kss++){
      bf16x8 af[4], bfr[4];
#pragma unroll
      for(int m=0;m<4;m++){
        int rr = wr*64 + m*16 + l15;
        int gg = kss*4 + lg;
        af[m] = *(const bf16x8*)(&sA[cur][rr*64 + ((gg^(rr&7))<<3)]);
      }
#pragma unroll
      for(int nn=0;nn<4;nn++){
        int rr = wc*64 + nn*16 + l15;
        int gg = kss*4 + lg;
        bfr[nn] = *(const bf16x8*)(&sB[cur][rr*64 + ((gg^(rr&7))<<3)]);
      }
#pragma unroll
      for(int m=0;m<4;m++)
#pragma unroll
        for(int nn=0;nn<4;nn++)
          acc[m][nn] = __builtin_amdgcn_mfma_f32_16x16x32_bf16(af[m], bfr[nn], acc[m][nn], 0,0,0);
    }
    if(t+1<4) stage_write(sA[cur^1], sB[cur^1], tid, r);
    __syncthreads();
  }
#undef KV_LOAD
  if (wr!=0) return;
  float* Cb = Cp + ((size_t)ks*8 + b)*8192;
#pragma unroll
  for(int m=0;m<2;m++)
#pragma unroll
    for(int nn=0;nn<4;nn++){
      int o_ = m*16 + (lg<<2);
      int c_ = nt*128 + wc*64 + nn*16 + l15;
#pragma unroll
      for(int i=0;i<4;i++) Cb[(size_t)(o_+i)*256 + c_] = acc[m][nn][i];
    }
}

__global__ __launch_bounds__(256) void kv_combine16(const float* __restrict__ p,
    float* __restrict__ o)
{
  int i = blockIdx.x*256 + threadIdx.x;
  float s = 0.f;
#pragma unroll
  for(int ks=0;ks<16;ks++) s += p[(size_t)ks*65536 + i];
  o[i] = s;
}

// ---- split-bf16 3-pass GEMM (pw conv) — unchanged from round 3
template<int KTILES, int KSPLIT, int OMODE>
__global__ __launch_bounds__(256,2) void gemm3(
    const u16* __restrict__ Ah, const u16* __restrict__ Al, int ldA, long sAb,
    const u16* __restrict__ Bh, const u16* __restrict__ Bl, int ldB, long sBb,
    float* __restrict__ Cf)
{
  __shared__ __align__(16) u16 sA[2][8192];
  __shared__ __align__(16) u16 sB[2][8192];
  int tid = threadIdx.x;
  int nt = blockIdx.x, mt = blockIdx.y;
  int b  = blockIdx.z / KSPLIT, ks = blockIdx.z % KSPLIT;
  long koff = (long)ks * (KTILES*64);
  const u16* A0 = Ah + (size_t)b*sAb + (size_t)mt*128*ldA + koff;
  const u16* A1 = Al + (size_t)b*sAb + (size_t)mt*128*ldA + koff;
  const u16* B0 = Bh + (size_t)b*sBb + (size_t)nt*128*ldB + koff;
  const u16* B1 = Bl + (size_t)b*sBb + (size_t)nt*128*ldB + koff;
  int w = tid>>6, l = tid&63;
  int wr = w>>1, wc = w&1;
  int l15 = l&15, lg = l>>4;
  f32x4 acc[4][4] = {};
  StageRegs r;
  for(int pass=0; pass<3; ++pass){
    const u16* gA = (pass==2) ? A1 : A0;
    const u16* gB = (pass==1) ? B1 : B0;
    stage_load(gA, ldA, gB, ldB, tid, r);
    stage_write(sA[0], sB[0], tid, r);
    __syncthreads();
    for(int t=0;t<KTILES;t++){
      int cur = t&1;
      if(t+1<KTILES) stage_load(gA + (t+1)*64, ldA, gB + (t+1)*64, ldB, tid, r);
#pragma unroll
      for(int kss=0;kss<2;kss++){
        bf16x8 af[4], bfr[4];
#pragma unroll
        for(int m=0;m<4;m++){
          int row = wr*64 + m*16 + l15;
          int g = kss*4 + lg;
          af[m] = *(const bf16x8*)(&sA[cur][row*64 + ((g^(row&7))<<3)]);
        }
#pragma unroll
        for(int nn=0;nn<4;nn++){
          int row = wc*64 + nn*16 + l15;
          int g = kss*4 + lg;
          bfr[nn] = *(const bf16x8*)(&sB[cur][row*64 + ((g^(row&7))<<3)]);
        }
#pragma unroll
        for(int m=0;m<4;m++)
#pragma unroll
          for(int nn=0;nn<4;nn++)
            acc[m][nn] = __builtin_amdgcn_mfma_f32_16x16x32_bf16(af[m], bfr[nn], acc[m][nn], 0,0,0);
      }
      if(t+1<KTILES) stage_write(sA[cur^1], sB[cur^1], tid, r);
      __syncthreads();
    }
  }
  int obase = mt*128 + wr*64;
  int nbase = nt*128 + wc*64;
  if (OMODE==0){
    size_t Mrows = (size_t)gridDim.y*128;
#pragma unroll
    for(int m=0;m<4;m++)
#pragma unroll
      for(int nn=0;nn<4;nn++){
        int o_ = obase + m*16 + (lg<<2);
        int n_ = nbase + nn*16 + l15;
        float* dst = Cf + (((size_t)b*Mrows + o_)<<12) + n_;
#pragma unroll
        for(int i=0;i<4;i++) dst[(size_t)i<<12] = acc[m][nn][i];
      }
  } else {
    int gridB = gridDim.z / KSPLIT;
    float* Cb = Cf + ((size_t)ks*gridB + b)*65536;
#pragma unroll
    for(int m=0;m<4;m++)
#pragma unroll
      for(int nn=0;nn<4;nn++){
        int o_ = obase + m*16 + (lg<<2);
        int n_ = nbase + nn*16 + l15;
#pragma unroll
        for(int i=0;i<4;i++) Cb[(size_t)(o_+i)*256 + n_] = acc[m][nn][i];
      }
  }
}

// ---- symmetric-energy variant: C = Z·Z^T, compute 3 of 4 128-blocks,
// mirror the off-diagonal. grid (3,1,8*16). OMODE2-style K-split partials.
__global__ __launch_bounds__(256,2) void gemm3_sym(
    const u16* __restrict__ Zh, const u16* __restrict__ Zl,
    float* __restrict__ Cf)
{
  __shared__ __align__(16) u16 sA[2][8192];
  __shared__ __align__(16) u16 sB[2][8192];
  int tid = threadIdx.x;
  int pair = blockIdx.x;                       // 0:(0,0) 1:(1,1) 2:(1,0)+mirror
  int nt = (pair==0) ? 0 : (pair==1 ? 1 : 0);
  int mt = (pair==0) ? 0 : 1;
  int b  = blockIdx.z >> 4, ks = blockIdx.z & 15;
  long koff = (long)ks * 256;
  const u16* A0 = Zh + (size_t)b*1048576 + (size_t)mt*128*4096 + koff;
  const u16* A1 = Zl + (size_t)b*1048576 + (size_t)mt*128*4096 + koff;
  const u16* B0 = Zh + (size_t)b*1048576 + (size_t)nt*128*4096 + koff;
  const u16* B1 = Zl + (size_t)b*1048576 + (size_t)nt*128*4096 + koff;
  int w = tid>>6, l = tid&63;
  int wr = w>>1, wc = w&1;
  int l15 = l&15, lg = l>>4;
  f32x4 acc[4][4] = {};
  StageRegs r;
  for(int pass=0; pass<3; ++pass){
    const u16* gA = (pass==2) ? A1 : A0;
    const u16* gB = (pass==1) ? B1 : B0;
    stage_load(gA, 4096, gB, 4096, tid, r);
    stage_write(sA[0], sB[0], tid, r);
    __syncthreads();
    for(int t=0;t<4;t++){
      int cur = t&1;
      if(t+1<4) stage_load(gA + (t+1)*64, 4096, gB + (t+1)*64, 4096, tid, r);
#pragma unroll
      for(int kss=0;kss<2;kss++){
        bf16x8 af[4], bfr[4];
#pragma unroll
        for(int m=0;m<4;m++){
          int row = wr*64 + m*16 + l15;
          int g = kss*4 + lg;
          af[m] = *(const bf16x8*)(&sA[cur][row*64 + ((g^(row&7))<<3)]);
        }
#pragma unroll
        for(int nn=0;nn<4;nn++){
          int row = wc*64 + nn*16 + l15;
          int g = kss*4 + lg;
          bfr[nn] = *(const bf16x8*)(&sB[cur][row*64 + ((g^(row&7))<<3)]);
        }
#pragma unroll
        for(int m=0;m<4;m++)
#pragma unroll
          for(int nn=0;nn<4;nn++)
            acc[m][nn] = __builtin_amdgcn_mfma_f32_16x16x32_bf16(af[m], bfr[nn], acc[m][nn], 0,0,0);
      }
      if(t+1<4) stage_write(sA[cur^1], sB[cur^1], tid, r);
      __syncthreads();
    }
  }
  float* Cb = Cf + ((size_t)ks*8 + b)*65536;
  int obase = mt*128 + wr*64;
  int nbase = nt*128 + wc*64;
#pragma unroll
  for(int m=0;m<4;m++)
#pragma unroll
    for(int nn=0;nn<4;nn++){
      int o_ = obase + m*16 + (lg<<2);
      int n_ = nbase + nn*16 + l15;
#pragma unroll
      for(int i=0;i<4;i++) Cb[(size_t)(o_+i)*256 + n_] = acc[m][nn][i];
      if (pair==2){                           // mirror into (0,1) block
        float4 v = { acc[m][nn][0], acc[m][nn][1], acc[m][nn][2], acc[m][nn][3] };
        *(float4*)&Cb[(size_t)n_*256 + o_] = v;
      }
    }
}

// ============================================================================
// fused MLP: out = bn2(w2 · relu6(bn1(w1 · px))) + residual.  [round 6]
// Block = 64 pixels, 4 waves. LDS: px 32K + w1half 64K + H 16K = 112 KB.
// FIN 0: out[ACT+idx] = yin + y2.  FIN 1: out[idx] = xin + x2 + out[ACT+idx].
// ============================================================================
template<int FIN>
__global__ __launch_bounds__(256,1) void mlp_fused(
    const u16* __restrict__ px, const u16* __restrict__ w1b,
    const u16* __restrict__ w2b,
    const float* __restrict__ b1, const float* __restrict__ s1,
    const float* __restrict__ t1, const float* __restrict__ b2,
    const float* __restrict__ s2, const float* __restrict__ t2,
    const float* __restrict__ zin, float* __restrict__ out)
{
  __shared__ __align__(16) u16 sPx[64*256];   // [n][c] swizzled
  __shared__ __align__(16) u16 sW1[128*256];  // [h][c] swizzled
  __shared__ __align__(16) u16 sH [64*128];   // [n][h] 8B-XOR swizzled
  int tid = threadIdx.x;
  int n0 = blockIdx.x*64, b = blockIdx.z;
  int w = tid>>6, l = tid&63, l15 = l&15, lg = l>>4;
  // stage px tile [64 n][256 c] (coalesced 16B)
  const u16* gpx = px + (((size_t)b*4096 + n0)<<8);
#pragma unroll
  for(int i=0;i<8;i++){
    int flat = tid + i*256;
    int row = flat>>5, g = flat&31;
    *(int4*)&sPx[row*256 + ((g ^ (row&7))<<3)] = *(const int4*)(gpx + row*256 + g*8);
  }
  f32x4 acc[4][4] = {};
  int cw = w*64, hw = w*32;
  for(int q=0;q<4;q++)
  for(int hh=0;hh<2;hh++){
    int hq = q*256 + hh*128;
    // stage w1 half [128 h][256 c]
    const u16* gw1 = w1b + (size_t)hq*256;
#pragma unroll
    for(int i=0;i<16;i++){
      int flat = tid + i*256;
      int row = flat>>5, g = flat&31;
      *(int4*)&sW1[row*256 + ((g ^ (row&7))<<3)] = *(const int4*)(gw1 + row*256 + g*8);
    }
    __syncthreads();                          // barrier1: w1 ready, sH free
    // GEMM1: H[128h][64n], wave w owns h rows hw..hw+31
    f32x4 a1[2][4] = {};
#pragma unroll
    for(int kst=0;kst<8;kst++){
      bf16x8 af[2], bfr[4];
#pragma unroll
      for(int mi=0;mi<2;mi++){
        int row = hw + mi*16 + l15;
        int g = kst*4 + lg;
        af[mi] = *(const bf16x8*)&sW1[row*256 + ((g^(row&7))<<3)];
      }
#pragma unroll
      for(int nn=0;nn<4;nn++){
        int row = nn*16 + l15;
        int g = kst*4 + lg;
        bfr[nn] = *(const bf16x8*)&sPx[row*256 + ((g^(row&7))<<3)];
      }
#pragma unroll
      for(int mi=0;mi<2;mi++)
#pragma unroll
        for(int nn=0;nn<4;nn++)
          a1[mi][nn] = __builtin_amdgcn_mfma_f32_16x16x32_bf16(af[mi], bfr[nn], a1[mi][nn], 0,0,0);
    }
    // prefetch w2 fragments (A operand for GEMM2) from L2
    int4 w2r[4][4];
#pragma unroll
    for(int kst=0;kst<4;kst++)
#pragma unroll
      for(int mi=0;mi<4;mi++){
        int row = cw + mi*16 + l15;
        w2r[kst][mi] = *(const int4*)(w2b + (size_t)row*1024 + hq + kst*32 + lg*8);
      }
    // H write: bn1 + relu6 -> bf16, n-major, 8B XOR swizzle
#pragma unroll
    for(int mi=0;mi<2;mi++)
#pragma unroll
      for(int nn=0;nn<4;nn++){
        int n_ = nn*16 + l15;
        int hbase = hw + mi*16 + (lg<<2);
        int ho = hq + hbase;
        union{ u16 u[4]; uint2 v; } pk;
#pragma unroll
        for(int i=0;i<4;i++){
          float a2 = (a1[mi][nn][i] + b1[ho+i])*s1[ho+i] + t1[ho+i];
          pk.u[i] = f2bu(fminf(fmaxf(a2,0.f),6.f));
        }
        int o8 = hbase>>2;
        *(uint2*)&sH[n_*128 + ((o8 ^ ((n_&7)<<1))<<2)] = pk.v;
      }
    __syncthreads();                          // barrier2: H ready, sW1 free
    // GEMM2: acc += w2_chunk @ H  (K=128)
#pragma unroll
    for(int kst=0;kst<4;kst++){
      bf16x8 bfr[4];
#pragma unroll
      for(int nn=0;nn<4;nn++){
        int n_ = nn*16 + l15;
        int o8 = kst*8 + lg*2;
        bfr[nn] = *(const bf16x8*)&sH[n_*128 + ((o8 ^ ((n_&7)<<1))<<2)];
      }
#pragma unroll
      for(int mi=0;mi<4;mi++){
        union { int4 i4; bf16x8 h8; } cvt; cvt.i4 = w2r[kst][mi];
#pragma unroll
        for(int nn=0;nn<4;nn++)
          acc[mi][nn] = __builtin_amdgcn_mfma_f32_16x16x32_bf16(cvt.h8, bfr[nn], acc[mi][nn], 0,0,0);
      }
    }
  }
  // epilogue: bn2 + residual, write d_out fp32 c-major
#pragma unroll
  for(int mi=0;mi<4;mi++)
#pragma unroll
    for(int nn=0;nn<4;nn++){
      int co = cw + mi*16 + (lg<<2);
      int n_ = n0 + nn*16 + l15;
#pragma unroll
      for(int i=0;i<4;i++){
        int c = co+i;
        size_t idx = (((size_t)b*256 + c)<<12) + n_;
        float v = (acc[mi][nn][i] + b2[c])*s2[c] + t2[c];
        if (FIN==0) out[ACT+idx] = zin[idx] + v;
        else        out[idx]     = zin[idx] + v + out[ACT+idx];
      }
    }
}

// ============================================================================
// conversion kernels
// ============================================================================
__global__ __launch_bounds__(256) void cvt_w(const float* __restrict__ s,
    u16* __restrict__ d)
{
  int i = blockIdx.x*256 + threadIdx.x;
  d[i] = f2bu(s[i]);
}
__global__ __launch_bounds__(256) void cvt_wsplit(const float* __restrict__ s,
    u16* __restrict__ dh, u16* __restrict__ dl)
{
  int i = blockIdx.x*256 + threadIdx.x;
  float v = s[i];
  u16 h = f2bu(v);
  dh[i] = h; dl[i] = f2bu(v - u2f(h));
}
__global__ __launch_bounds__(256) void cvt_qk(const float* __restrict__ q,
    const float* __restrict__ k, u16* __restrict__ A)
{
  int r = blockIdx.x, c = threadIdx.x;
  float v = 0.f;
  if (r < 32) v = q[r*256 + c];
  else if (r < 64) v = k[(r-32)*256 + c];
  A[r*256 + c] = f2bu(v);
}
__global__ __launch_bounds__(256) void cvt_split_nm(const float* __restrict__ x,
    u16* __restrict__ xh, u16* __restrict__ xl)
{
  int n  = blockIdx.x*256 + threadIdx.x;
  int c0 = blockIdx.y*16;
  int b  = blockIdx.z;
  union { u16 u[16]; uint4 q[2]; } ph, pl;
#pragma unroll
  for (int oo=0;oo<16;oo++){
    float v = x[(((size_t)b*256 + c0 + oo)<<12) + n];
    u16 h = f2bu(v);
    ph.u[oo] = h; pl.u[oo] = f2bu(v - u2f(h));
  }
  size_t o = (((size_t)b*4096 + n)<<8) + c0;
  *(uint4*)(xh+o) = ph.q[0]; *(uint4*)(xh+o+8) = ph.q[1];
  *(uint4*)(xl+o) = pl.q[0]; *(uint4*)(xl+o+8) = pl.q[1];
}
__global__ __launch_bounds__(256) void cvt_transpose(const u16* __restrict__ zc,
    u16* __restrict__ zn)
{
  int n  = blockIdx.x*256 + threadIdx.x;
  int c0 = blockIdx.y*16;
  int b  = blockIdx.z;
  union { u16 u[16]; uint4 q[2]; } pk;
#pragma unroll
  for (int oo=0;oo<16;oo++)
    pk.u[oo] = zc[(((size_t)b*256 + c0 + oo)<<12) + n];
  u16* dst = zn + (((size_t)b*4096 + n)<<8) + c0;
  *(uint4*)dst       = pk.q[0];
  *(uint4*)(dst + 8) = pk.q[1];
}

// ============================================================================
// depthwise 3x3 + conv BN + norm BN -> split hi/lo bf16 z1 (LDS-tiled, round 5)
// ============================================================================
__global__ __launch_bounds__(256) void dw_norm_tile(const float* __restrict__ pw,
    u16* __restrict__ zh, u16* __restrict__ zl, const float* __restrict__ dww,
    const float* __restrict__ cbs, const float* __restrict__ cbt,
    const float* __restrict__ ns, const float* __restrict__ nt)
{
  int bc = blockIdx.x;
  int c = bc & 255;
  __shared__ float sp[66*66];
  int tid = threadIdx.x;
  if (tid < 66){ sp[tid] = 0.f; sp[65*66 + tid] = 0.f; }
  if (tid >= 128 && tid < 192) sp[(tid-128+1)*66] = 0.f;
  if (tid >= 192)              sp[(tid-192+1)*66 + 65] = 0.f;
  const float* src = pw + ((size_t)bc << 12);
#pragma unroll
  for(int it=0; it<4; it++){
    int idx = tid + it*256;
    int r = idx >> 4, c4 = idx & 15;
    float4 v = *(const float4*)(src + (idx<<2));
    float* d = &sp[(r+1)*66 + 1 + (c4<<2)];
    d[0]=v.x; d[1]=v.y; d[2]=v.z; d[3]=v.w;
  }
  __syncthreads();
  const float* wp = dww + c*9;
  float w00=wp[0], w01=wp[1], w02=wp[2],
        w10=wp[3], w11=wp[4], w12=wp[5],
        w20=wp[6], w21=wp[7], w22=wp[8];
  float sc = cbs[c]*ns[c];
  float sh = cbt[c]*ns[c] + nt[c];
  int r  = tid >> 2;
  int c0 = (tid & 3) << 4;
  const float* row0 = &sp[r*66 + c0];
  const float* row1 = row0 + 66;
  const float* row2 = row1 + 66;
  union { u16 u[16]; uint4 q[2]; } ph, pl;
#pragma unroll
  for(int j=0;j<16;j++){
    float acc = w00*row0[j] + w01*row0[j+1] + w02*row0[j+2]
              + w10*row1[j] + w11*row1[j+1] + w12*row1[j+2]
              + w20*row2[j] + w21*row2[j+1] + w22*row2[j+2];
    float v = acc*sc + sh;
    u16 hi = f2bu(v);
    ph.u[j] = hi; pl.u[j] = f2bu(v - u2f(hi));
  }
  size_t o = ((size_t)bc << 12) + (r<<6) + c0;
  *(uint4*)(zh+o)   = ph.q[0]; *(uint4*)(zh+o+8) = ph.q[1];
  *(uint4*)(zl+o)   = pl.q[0]; *(uint4*)(zl+o+8) = pl.q[1];
}

// ---- softmax of (rowmax - e), summing 16 K-split partials; bf16 att out
__global__ __launch_bounds__(256) void softmax16(const float* __restrict__ Ep,
    u16* __restrict__ att)
{
  int bc = blockIdx.x;
  int b = bc>>8, c = bc&255;
  size_t base = (size_t)b*65536 + (size_t)c*256;
  int d = threadIdx.x;
  float ed = 0.f;
#pragma unroll
  for(int ks=0;ks<16;ks++) ed += Ep[base + (size_t)ks*524288 + d];
  __shared__ float red[4];
  int lane = d&63, wid = d>>6;
  float v = ed;
  for (int off=32;off;off>>=1) v = fmaxf(v, __shfl_down(v,off));
  if(lane==0) red[wid]=v;
  __syncthreads();
  float rowmax = fmaxf(fmaxf(red[0],red[1]),fmaxf(red[2],red[3]));
  __syncthreads();
  float s = rowmax - ed;
  float v2 = s;
  for (int off=32;off;off>>=1) v2 = fmaxf(v2, __shfl_down(v2,off));
  if(lane==0) red[wid]=v2;
  __syncthreads();
  float smax = fmaxf(fmaxf(red[0],red[1]),fmaxf(red[2],red[3]));
  __syncthreads();
  float p = expf(s - smax);
  float sv = p;
  for (int off=32;off;off>>=1) sv += __shfl_down(sv,off);
  if(lane==0) red[wid]=sv;
  __syncthreads();
  float sum = red[0]+red[1]+red[2]+red[3];
  att[((size_t)bc<<8)+d] = f2bu(p/sum);
}

// ============================================================================
// light epilogue (z1/other from hi/lo; s1 bf16), n-major bf16 px out
// ============================================================================
__global__ __launch_bounds__(256) void catt_px(const u16* __restrict__ zh,
    const u16* __restrict__ zl, const u16* __restrict__ oh,
    const u16* __restrict__ ol, const float* __restrict__ Qf,
    const float* __restrict__ KVf, const float* __restrict__ invb,
    const u16* __restrict__ s1b, const float* __restrict__ gkp,
    const float* __restrict__ gcp, const float* __restrict__ ns,
    const float* __restrict__ nt, u16* __restrict__ px)
{
  int n  = blockIdx.x*256 + threadIdx.x;
  int c0 = blockIdx.y*16;
  int b  = blockIdx.z;
  const float* qb  = Qf  + (((size_t)b*Mm)<<12) + n;
  const float* kvb = KVf + ((size_t)b<<13) + c0;
  float s2[16] = {};
#pragma unroll
  for (int m=0;m<Mm;m++){
    float qm = qb[(size_t)m<<12];
#pragma unroll
    for (int oo=0;oo<16;oo++) s2[oo] = fmaf(qm, kvb[m*256 + oo], s2[oo]);
  }
  float invv = invb[((size_t)b<<12)+n];
  float gk = gkp[0], gc = gcp[0];
  union { u16 u[16]; uint4 q[2]; } pk;
#pragma unroll
  for (int oo=0;oo<16;oo++){
    int c = c0+oo;
    size_t idx = (((size_t)b*256 + c)<<12) + n;
    float zv = u2f(zh[idx]) + u2f(zl[idx]);
    float ov = u2f(oh[idx]) + u2f(ol[idx]);
    float a = 2.f*zv + gc*u2f(s1b[idx]) + gk*s2[oo]*invv;
    pk.u[oo] = f2bu(ov*a*ns[c] + nt[c]);
  }
  u16* dst = px + (((size_t)b*4096 + n)<<8) + c0;
  *(uint4*)dst       = pk.q[0];
  *(uint4*)(dst + 8) = pk.q[1];
}

// ============================================================================
// small fp32 kernels (unchanged)
// ============================================================================
__global__ __launch_bounds__(256) void rowsum_lit(const float* __restrict__ A, float* __restrict__ out)
{
  int x = blockIdx.x;
  const float* ar = A + ((size_t)x << 12);
  float a = 0.f;
  for(int n=threadIdx.x; n<Nn; n+=256) a += ar[n];
  __shared__ float red[4];
  for(int off=32;off;off>>=1) a += __shfl_down(a,off);
  int lane = threadIdx.x&63, wid = threadIdx.x>>6;
  if(lane==0) red[wid]=a;
  __syncthreads();
  if(threadIdx.x==0) out[x] = red[0]+red[1]+red[2]+red[3];
}

__global__ __launch_bounds__(256) void inv_lit(const float* __restrict__ Qf,
    const float* __restrict__ Ks, float* __restrict__ invb)
{
  size_t idx = (size_t)blockIdx.x*256 + threadIdx.x;
  int b = (int)(idx>>12);
  const float* qb = Qf + ((size_t)b*Mm << 12) + (int)(idx&4095);
  const float* ks = Ks + b*Mm;
  float s = 0.f;
  for(int m=0;m<Mm;m++) s += qb[(size_t)m<<12]*(ks[m]+EPSc);
  invb[idx] = 1.f/s;
}

extern "C" void kernel_launch(void* const* d_in, const int* in_sizes, int n_in,
                              void* d_out, int out_size, void* d_ws, size_t ws_size,
                              hipStream_t stream)
{
  (void)in_sizes; (void)n_in; (void)out_size; (void)ws_size;
  const float* xin  = (const float*)d_in[0];
  const float* yin  = (const float*)d_in[1];
  const float* pw_w = (const float*)d_in[2];
  const float* dw_w = (const float*)d_in[3];
  const float* cbs  = (const float*)d_in[4];
  const float* cbt  = (const float*)d_in[5];
  const float* ns   = (const float*)d_in[6];
  const float* nt   = (const float*)d_in[7];
  const float* q_w  = (const float*)d_in[8];
  const float* k_w  = (const float*)d_in[9];
  const float* v_w  = (const float*)d_in[10];
  const float* gk   = (const float*)d_in[11];
  const float* gc   = (const float*)d_in[12];
  const float* fc1_w= (const float*)d_in[13];
  const float* fc1_b= (const float*)d_in[14];
  const float* bn1s = (const float*)d_in[15];
  const float* bn1t = (const float*)d_in[16];
  const float* fc2_w= (const float*)d_in[17];
  const float* fc2_b= (const float*)d_in[18];
  const float* bn2s = (const float*)d_in[19];
  const float* bn2t = (const float*)d_in[20];

  char* ws = (char*)d_ws;
  // ---- workspace (same proven 145,097,728-byte footprint) ----
  u16*   Vb    = (u16*)  (ws);
  float* KVp   = (float*)(ws + 16777216);
  u16*   Kb    = (u16*)  (ws + 20971520);
  float* Ep    = (float*)(ws);
  u16*   s1b16 = (u16*)  (ws);
  float* Apw   = (float*)(ws);                // phase1 pw output (fp32 32M)
  u16*   x1h   = (u16*)  (ws + 33554432);     // 32..48M bf16 c-major hi
  u16*   x1l   = (u16*)  (ws + 50331648);     // 48..64M lo
  u16*   y1h   = (u16*)  (ws + 67108864);     // 64..80M
  u16*   y1l   = (u16*)  (ws + 83886080);     // 80..96M
  u16*   px_y  = (u16*)  (ws + 100663296);    // 96..112M bf16 n-major
  u16*   px_x  = (u16*)  (ws + 117440512);    // 112..128M bf16 n-major
  u16*   xh_nm = (u16*)  (ws + 100663296);    // phase1 transient (over px_y)
  u16*   xl_nm = (u16*)  (ws + 117440512);    // phase1 transient (over px_x)
  u16*   z1b   = (u16*)  (ws + 117440512);    // phase2 transient (over px_x)
  float* Qf    = (float*)(ws + 134217728);    // 128..132M fp32 [8,32,4096]
  float* Kf    = (float*)(ws + 138412032);    // 132..136M
  u16*   pwh   = (u16*)  (ws + 134217728);    // phase1 only (over Qf): 128K
  u16*   pwl   = (u16*)  (ws + 134217728 + 131072);
  u16*   attb  = (u16*)  (ws + 142606336);    // 136..137M bf16 [8][256][256]
  u16*   fc1wb = (u16*)  (ws + 142606336);    // phase3 overlay: 512K
  u16*   fc2wb = (u16*)  (ws + 142606336 + 524288); // 512K
  float* KVf   = (float*)(ws + 143654912);    // 256K fp32 [8,32,256]
  float* Ksf   = (float*)(ws + 143917056);    // 1K
  float* invb  = (float*)(ws + 143918080);    // 128K
  u16*   vwb   = (u16*)  (ws + 144049152);    // 128K (stable)
  u16*   Aqk   = (u16*)  (ws + 144049152 + 131072); // 64K stable

  dim3 blk(256);
  dim3 gPX(16,16,8);
  dim3 gPW(32,2,8), gEn(3,1,128), gG256(32,2,8), gQKg(32,1,8), gKVg(2,1,128);
  dim3 gMLP(64,1,8);

  // ---- static weight conversions (stable slots)
  cvt_w<<<dim3(256),blk,0,stream>>>(v_w, vwb);
  cvt_qk<<<dim3(128),blk,0,stream>>>(q_w, k_w, Aqk);

  // ---- Phase 1: z1 = norm(bn(dw3(pw(z)))) via split-bf16 MFMA (fp32-equiv)
  cvt_wsplit<<<dim3(256),blk,0,stream>>>(pw_w, pwh, pwl);
  for (int im=0;im<2;im++){
    const float* in = (im==0) ? xin : yin;
    u16* zh = (im==0) ? x1h : y1h;
    u16* zl = (im==0) ? x1l : y1l;
    cvt_split_nm<<<gPX,blk,0,stream>>>(in, xh_nm, xl_nm);
    gemm3<4,1,0><<<gPW,blk,0,stream>>>(pwh, pwl, 256, 0,
                                       xh_nm, xl_nm, 256, 1048576, Apw);
    dw_norm_tile<<<dim3(2048),blk,0,stream>>>(Apw, zh, zl, dw_w, cbs, cbt, ns, nt);
  }

  // ---- Phase 2
  for (int t=0;t<2;t++){
    const u16* zh = (t==0) ? x1h : y1h;
    const u16* zl = (t==0) ? x1l : y1l;
    const u16* oh = (t==0) ? y1h : x1h;
    const u16* ol = (t==0) ? y1l : x1l;
    u16* pxout    = (t==0) ? px_y : px_x;
    cvt_transpose<<<gPX,blk,0,stream>>>(zh, z1b);
    qk_gemm<<<gQKg,blk,0,stream>>>(Aqk, z1b, Qf, Kf, Kb);
    gemm_bf16<256,3><<<gG256,blk,0,stream>>>(vwb, 0, z1b, nullptr, Vb,
                                             nullptr, nullptr, nullptr);      // V bf16
    kv_gemm<<<gKVg,blk,0,stream>>>(Kb, Vb, KVp);
    kv_combine16<<<dim3(256),blk,0,stream>>>(KVp, KVf);
    rowsum_lit<<<dim3(256),blk,0,stream>>>(Kf, Ksf);
    inv_lit<<<dim3(128),blk,0,stream>>>(Qf, Ksf, invb);
    // energy = z.z^T via split-bf16 symmetric (3/4 blocks + mirror)
    gemm3_sym<<<gEn,blk,0,stream>>>(zh, zl, Ep);
    softmax16<<<dim3(2048),blk,0,stream>>>(Ep, attb);
    gemm_bf16<256,3><<<gG256,blk,0,stream>>>(attb, 65536, z1b, nullptr, s1b16,
                                             nullptr, nullptr, nullptr);      // s1 bf16
    catt_px<<<gPX,blk,0,stream>>>(zh, zl, oh, ol, Qf, KVf, invb, s1b16,
                                  gk, gc, ns, nt, pxout);
  }

  // ---- Phase 3: fused MLPs (px -> d_out directly; no hid/accb round-trip)
  cvt_w<<<dim3(1024),blk,0,stream>>>(fc1_w, fc1wb);
  cvt_w<<<dim3(1024),blk,0,stream>>>(fc2_w, fc2wb);
  mlp_fused<0><<<gMLP,blk,0,stream>>>(px_y, fc1wb, fc2wb, fc1_b, bn1s, bn1t,
                                      fc2_b, bn2s, bn2t, yin, (float*)d_out);
  mlp_fused<1><<<gMLP,blk,0,stream>>>(px_x, fc1wb, fc2wb, fc1_b, bn1s, bn1t,
                                      fc2_b, bn2s, bn2t, xin, (float*)d_out);
}